// Round 2
// baseline (278.873 us; speedup 1.0000x reference)
//
#include <hip/hip_runtime.h>
#include <hip/hip_bf16.h>

typedef __attribute__((ext_vector_type(8))) short short8;
typedef __attribute__((ext_vector_type(4))) float f32x4;

__device__ inline short f2bf(float f) {
  __hip_bfloat16 h = __float2bfloat16(f);
  return __builtin_bit_cast(short, h);
}

__device__ inline f32x4 mfma16(short8 a, short8 b, f32x4 c) {
  return __builtin_amdgcn_mfma_f32_16x16x32_bf16(a, b, c, 0, 0, 0);
}

// ---------------- constants ----------------
#define Bsz 16
#define Cc 128
#define HW 1024
#define NHh 4
#define CONDc 32
#define KIN 160      // C + COND
#define KOUT 512     // C * NH
#define CH3 768      // (NH+2)*C
#define SCALE_Q 0.08838834764831845f   // 1/sqrt(128)

// ---------------- weight prep: transpose + bf16 ----------------
__global__ __launch_bounds__(256) void k_prep_w(
    const float* __restrict__ W0, const float* __restrict__ W1,
    const float* __restrict__ W2, const float* __restrict__ W3,
    short* __restrict__ Wt0, short* __restrict__ Wt1,
    short* __restrict__ Wt2, short* __restrict__ Wt3) {
  int i = blockIdx.x * 256 + threadIdx.x;
  if (i < KOUT * KIN) {           // Wt[ko][c] = W[c][ko]
    int ko = i / KIN, c = i % KIN;
    Wt0[i] = f2bf(W0[c * KOUT + ko]);
    Wt1[i] = f2bf(W1[c * KOUT + ko]);
    Wt2[i] = f2bf(W2[c * KOUT + ko]);
  }
  if (i < Cc * CH3) {             // Wt3[ko][ch] = W3[ch][ko]
    int ko = i / CH3, ch = i % CH3;
    Wt3[i] = f2bf(W3[ch * Cc + ko]);
  }
}

// ---------------- groupnorm stats ----------------
__global__ __launch_bounds__(256) void k_gn_stats(const float* __restrict__ x,
                                                  float* __restrict__ stats) {
  int b = blockIdx.x >> 5, g = blockIdx.x & 31;
  int tid = threadIdx.x, lane = tid & 63, wid = tid >> 6;
  long base = ((long)b * Cc + g * 4) * HW;
  float s = 0.f, sq = 0.f;
#pragma unroll
  for (int i = 0; i < 16; i++) {
    float v = x[base + tid + i * 256];
    s += v; sq += v * v;
  }
#pragma unroll
  for (int d = 1; d < 64; d <<= 1) {
    s += __shfl_xor(s, d);
    sq += __shfl_xor(sq, d);
  }
  __shared__ float ls[8];
  if (lane == 0) { ls[wid] = s; ls[wid + 4] = sq; }
  __syncthreads();
  if (tid == 0) {
    float ts = ls[0] + ls[1] + ls[2] + ls[3];
    float tq = ls[4] + ls[5] + ls[6] + ls[7];
    float mu = ts / 4096.f;
    float var = tq / 4096.f - mu * mu;
    var = var < 0.f ? 0.f : var;
    stats[(b * 32 + g) * 2] = mu;
    stats[(b * 32 + g) * 2 + 1] = rsqrtf(var + 1e-6f);
  }
}

// ---------------- GN apply + concat conds + transpose -> XqT/XkT [b][hw][160] bf16 ----------------
__global__ __launch_bounds__(256) void k_build_xt(
    const float* __restrict__ x, const float* __restrict__ q_cond,
    const float* __restrict__ k_a, const float* __restrict__ k_b,
    const float* __restrict__ gsc, const float* __restrict__ gbi,
    const float* __restrict__ stats,
    short* __restrict__ XqT, short* __restrict__ XkT) {
  int b = blockIdx.y, hw0 = blockIdx.x * 64, tid = threadIdx.x;
  __shared__ short xq[64][KIN];
  __shared__ short xk[64][KIN];
  // h part: 128 c x 64 hw
#pragma unroll
  for (int i = 0; i < 8; i++) {
    int ci = tid + i * 256;            // 0..2047
    int c = ci >> 4, hwo = (ci & 15) * 4;
    float4 xv = *(const float4*)(x + ((long)b * Cc + c) * HW + hw0 + hwo);
    int g = c >> 2;
    float mu = stats[(b * 32 + g) * 2];
    float rs = stats[(b * 32 + g) * 2 + 1];
    float sc = gsc[c] * rs;
    float bi = gbi[c] - mu * sc;
    short v0 = f2bf(xv.x * sc + bi);
    short v1 = f2bf(xv.y * sc + bi);
    short v2 = f2bf(xv.z * sc + bi);
    short v3 = f2bf(xv.w * sc + bi);
    xq[hwo + 0][c] = v0; xk[hwo + 0][c] = v0;
    xq[hwo + 1][c] = v1; xk[hwo + 1][c] = v1;
    xq[hwo + 2][c] = v2; xk[hwo + 2][c] = v2;
    xq[hwo + 3][c] = v3; xk[hwo + 3][c] = v3;
  }
  // cond part: 32 c x 64 hw
#pragma unroll
  for (int i = 0; i < 2; i++) {
    int ci = tid + i * 256;            // 0..511
    int cc = ci >> 4, hwo = (ci & 15) * 4;
    long src = ((long)(b >> 1) * CONDc + cc) * HW + hw0 + hwo;
    float4 qv = *(const float4*)(q_cond + src);
    const float* ks = (b & 1) ? k_b : k_a;
    float4 kv = *(const float4*)(ks + src);
    xq[hwo + 0][Cc + cc] = f2bf(qv.x); xk[hwo + 0][Cc + cc] = f2bf(kv.x);
    xq[hwo + 1][Cc + cc] = f2bf(qv.y); xk[hwo + 1][Cc + cc] = f2bf(kv.y);
    xq[hwo + 2][Cc + cc] = f2bf(qv.z); xk[hwo + 2][Cc + cc] = f2bf(kv.z);
    xq[hwo + 3][Cc + cc] = f2bf(qv.w); xk[hwo + 3][Cc + cc] = f2bf(kv.w);
  }
  __syncthreads();
  // write out: 64 rows x 160 ch (320B rows)
#pragma unroll
  for (int i = 0; i < 5; i++) {
    int ci = tid + i * 256;            // 0..1279
    int row = ci / 20, ch = (ci % 20) * 8;
    long dst = ((long)b * HW + hw0 + row) * KIN + ch;
    *(short8*)(XqT + dst) = *(const short8*)(&xq[row][ch]);
    *(short8*)(XkT + dst) = *(const short8*)(&xk[row][ch]);
  }
}

// ---------------- generic bf16 GEMM: D[m][n] = sum_k A[m][k]*B[n][k] (+bias)*scale ----------------
// 128x128 tile, 4 waves (2x2), each wave 64x64. LDS swizzle for 64B rows.
__device__ inline int gswz(int row, int kb) {
  return row * 64 + (kb ^ (((row >> 1) & 3) << 4));
}

__global__ __launch_bounds__(256) void k_gemm(
    const short* __restrict__ A, long sA,
    const short* __restrict__ B, long sB,
    short* __restrict__ D, long sD,
    const float* __restrict__ bias, int bias_on_m, float scale,
    int M, int N, int K) {
  int bz = blockIdx.z;
  A += bz * sA; B += bz * sB; D += bz * sD;
  int m0 = blockIdx.y * 128, n0 = blockIdx.x * 128;
  int tid = threadIdx.x, lane = tid & 63, wid = tid >> 6;
  int wm = (wid >> 1) * 64, wn = (wid & 1) * 64;
  int lm = lane & 15, kg = lane >> 4;
  __shared__ short lA[128 * 32];
  __shared__ short lB[128 * 32];
  f32x4 acc[4][4] = {};
  for (int k0 = 0; k0 < K; k0 += 32) {
    __syncthreads();
#pragma unroll
    for (int i = 0; i < 2; i++) {
      int ci = tid + i * 256;          // 0..511
      int row = ci >> 2, kb = (ci & 3) * 16;
      *(short8*)((char*)lA + gswz(row, kb)) =
          *(const short8*)(A + (long)(m0 + row) * K + k0 + (kb >> 1));
      *(short8*)((char*)lB + gswz(row, kb)) =
          *(const short8*)(B + (long)(n0 + row) * K + k0 + (kb >> 1));
    }
    __syncthreads();
    short8 af[4], bfr[4];
    int kb = kg * 16;
#pragma unroll
    for (int t = 0; t < 4; t++) {
      af[t] = *(const short8*)((char*)lA + gswz(wm + t * 16 + lm, kb));
      bfr[t] = *(const short8*)((char*)lB + gswz(wn + t * 16 + lm, kb));
    }
#pragma unroll
    for (int mt = 0; mt < 4; mt++)
#pragma unroll
      for (int nt = 0; nt < 4; nt++)
        acc[mt][nt] = mfma16(af[mt], bfr[nt], acc[mt][nt]);
  }
#pragma unroll
  for (int mt = 0; mt < 4; mt++)
#pragma unroll
    for (int nt = 0; nt < 4; nt++) {
      f32x4 c = acc[mt][nt];
      int n = n0 + wn + nt * 16 + lm;
#pragma unroll
      for (int r = 0; r < 4; r++) {
        int m = m0 + wm + mt * 16 + kg * 4 + r;
        float val = c[r] + bias[bias_on_m ? m : n];
        val *= scale;
        D[(long)m * N + n] = f2bf(val);
      }
    }
}

// ---------------- final GEMM: out = x + hhT*Wt3 + b3 (f32 out) ----------------
__global__ __launch_bounds__(256) void k_gemm_final(
    const short* __restrict__ A,      // Wt3 [128][768]
    const short* __restrict__ Ball,   // hhT [16][1024][768]
    const float* __restrict__ x, const float* __restrict__ bias,
    float* __restrict__ out) {
  int b = blockIdx.z;
  const short* B = Ball + (long)b * HW * CH3;
  int n0 = blockIdx.x * 128;
  int tid = threadIdx.x, lane = tid & 63, wid = tid >> 6;
  int wm = (wid >> 1) * 64, wn = (wid & 1) * 64;
  int lm = lane & 15, kg = lane >> 4;
  __shared__ short lA[128 * 32];
  __shared__ short lB[128 * 32];
  f32x4 acc[4][4] = {};
  for (int k0 = 0; k0 < CH3; k0 += 32) {
    __syncthreads();
#pragma unroll
    for (int i = 0; i < 2; i++) {
      int ci = tid + i * 256;
      int row = ci >> 2, kb = (ci & 3) * 16;
      *(short8*)((char*)lA + gswz(row, kb)) =
          *(const short8*)(A + (long)row * CH3 + k0 + (kb >> 1));
      *(short8*)((char*)lB + gswz(row, kb)) =
          *(const short8*)(B + (long)(n0 + row) * CH3 + k0 + (kb >> 1));
    }
    __syncthreads();
    short8 af[4], bfr[4];
    int kb = kg * 16;
#pragma unroll
    for (int t = 0; t < 4; t++) {
      af[t] = *(const short8*)((char*)lA + gswz(wm + t * 16 + lm, kb));
      bfr[t] = *(const short8*)((char*)lB + gswz(wn + t * 16 + lm, kb));
    }
#pragma unroll
    for (int mt = 0; mt < 4; mt++)
#pragma unroll
      for (int nt = 0; nt < 4; nt++)
        acc[mt][nt] = mfma16(af[mt], bfr[nt], acc[mt][nt]);
  }
#pragma unroll
  for (int mt = 0; mt < 4; mt++)
#pragma unroll
    for (int nt = 0; nt < 4; nt++) {
      f32x4 c = acc[mt][nt];
      int n = n0 + wn + nt * 16 + lm;
#pragma unroll
      for (int r = 0; r < 4; r++) {
        int m = wm + mt * 16 + kg * 4 + r;   // M=128, m0=0
        float val = c[r] + bias[m];
        long oidx = ((long)b * Cc + m) * HW + n;
        out[oidx] = x[oidx] + val;
      }
    }
}

// ---------------- fused flash attention ----------------
// grid: (16 q-tiles, 96 problems). block 256 = 4 waves x 16 q rows.
__global__ __launch_bounds__(256) void k_attn(
    const short* __restrict__ qT, const short* __restrict__ kT,
    const short* __restrict__ v, short* __restrict__ hhT) {
  int p = blockIdx.y;
  int b4 = p / 24, rem = p % 24, j = rem >> 2, e = rem & 3;
  static const int qsl[6] = {0, 1, 2, 3, 0, 2};
  static const int kvl[6] = {1, 0, 3, 2, 2, 0};
  int bq = b4 * 4 + qsl[j];
  int bkv = b4 * 4 + kvl[j];
  int midx = 4 * j + e;
  int bo = b4 * 4 + midx / 6;
  int chb = (midx % 6) * Cc;
  int q0 = blockIdx.x * 64;
  int tid = threadIdx.x, lane = tid & 63, wid = tid >> 6;
  int lm = lane & 15, kg = lane >> 4;

  __shared__ char lK[64 * 256];     // K^T tile [kv][c] bf16, swizzled
  __shared__ char lV[128 * 128];    // V tile [c][kv] bf16, swizzled
  __shared__ char lP[4][2048];      // per-wave P [q][kv] bf16, swizzled

  // Q fragments: A[m=q][k=c], 4 k-steps of 32
  short8 qf[4];
  const short* qbase =
      qT + ((long)bq * HW + q0 + wid * 16 + lm) * KOUT + e * Cc + kg * 8;
#pragma unroll
  for (int ks = 0; ks < 4; ks++) qf[ks] = *(const short8*)(qbase + ks * 32);

  float mrow[4] = {-3e38f, -3e38f, -3e38f, -3e38f};
  float lsum[4] = {0.f, 0.f, 0.f, 0.f};
  f32x4 oacc[8] = {};

  for (int kvt = 0; kvt < 16; kvt++) {
    int kv0 = kvt * 64;
    __syncthreads();
    // stage K^T tile: 64 rows x 256B
#pragma unroll
    for (int i = 0; i < 4; i++) {
      int ci = tid + i * 256;
      int row = ci >> 4, cb = (ci & 15) * 16;
      *(short8*)(lK + row * 256 + (cb ^ ((row & 7) << 4))) =
          *(const short8*)(kT + ((long)bkv * HW + kv0 + row) * KOUT + e * Cc + (cb >> 1));
    }
    // stage V tile: 128 rows x 128B
#pragma unroll
    for (int i = 0; i < 4; i++) {
      int ci = tid + i * 256;
      int row = ci >> 3, kvb = (ci & 7) * 16;
      *(short8*)(lV + row * 128 + (kvb ^ ((row & 7) << 4))) =
          *(const short8*)(v + ((long)bkv * KOUT + e * Cc + row) * HW + kv0 + (kvb >> 1));
    }
    __syncthreads();
    // S = Q^T K : D[q 16][kv 64]
    f32x4 s[4] = {};
#pragma unroll
    for (int ks = 0; ks < 4; ks++) {
      int cbyte = ks * 64 + kg * 16;
#pragma unroll
      for (int nt = 0; nt < 4; nt++) {
        int row = nt * 16 + lm;
        short8 kf = *(const short8*)(lK + row * 256 + (cbyte ^ ((row & 7) << 4)));
        s[nt] = mfma16(qf[ks], kf, s[nt]);
      }
    }
    // online softmax, row q = kg*4 + r
#pragma unroll
    for (int r = 0; r < 4; r++) {
      float mx = fmaxf(fmaxf(s[0][r], s[1][r]), fmaxf(s[2][r], s[3][r]));
#pragma unroll
      for (int d = 1; d < 16; d <<= 1) mx = fmaxf(mx, __shfl_xor(mx, d));
      float mnew = fmaxf(mrow[r], mx);
      float corr = __expf(mrow[r] - mnew);
      mrow[r] = mnew;
      float ps = 0.f;
#pragma unroll
      for (int nt = 0; nt < 4; nt++) {
        float pv = __expf(s[nt][r] - mnew);
        s[nt][r] = pv;
        ps += pv;
      }
#pragma unroll
      for (int d = 1; d < 16; d <<= 1) ps += __shfl_xor(ps, d);
      lsum[r] = lsum[r] * corr + ps;
#pragma unroll
      for (int ct = 0; ct < 8; ct++) oacc[ct][r] *= corr;
    }
    // P -> per-wave LDS [q][kv] bf16 swizzled
#pragma unroll
    for (int nt = 0; nt < 4; nt++)
#pragma unroll
      for (int r = 0; r < 4; r++) {
        int q = kg * 4 + r;
        int kvb = (nt * 16 + lm) * 2;
        *(short*)(lP[wid] + q * 128 + (kvb ^ ((q & 7) << 4))) = f2bf(s[nt][r]);
      }
    // O += P V : D[q 16][c 128]
#pragma unroll
    for (int ks2 = 0; ks2 < 2; ks2++) {
      int kvbyte = ks2 * 64 + kg * 16;
      short8 pf = *(const short8*)(lP[wid] + lm * 128 + (kvbyte ^ ((lm & 7) << 4)));
#pragma unroll
      for (int ct = 0; ct < 8; ct++) {
        int row = ct * 16 + lm;
        short8 vf = *(const short8*)(lV + row * 128 + (kvbyte ^ ((row & 7) << 4)));
        oacc[ct] = mfma16(pf, vf, oacc[ct]);
      }
    }
  }
  // epilogue: O^T[q][c] -> hhT[bo][q][chb + c]
  float inv[4];
#pragma unroll
  for (int r = 0; r < 4; r++) inv[r] = 1.f / lsum[r];
  long obase = ((long)bo * HW + q0 + wid * 16 + kg * 4) * CH3 + chb;
#pragma unroll
  for (int ct = 0; ct < 8; ct++)
#pragma unroll
    for (int r = 0; r < 4; r++)
      hhT[obase + (long)r * CH3 + ct * 16 + lm] = f2bf(oacc[ct][r] * inv[r]);
}

// ---------------- launcher ----------------
extern "C" void kernel_launch(void* const* d_in, const int* in_sizes, int n_in,
                              void* d_out, int out_size, void* d_ws, size_t ws_size,
                              hipStream_t stream) {
  const float* x      = (const float*)d_in[0];
  const float* q_cond = (const float*)d_in[1];
  const float* k_a    = (const float*)d_in[2];
  const float* k_b    = (const float*)d_in[3];
  const float* gsc    = (const float*)d_in[4];
  const float* gbi    = (const float*)d_in[5];
  const float* W0     = (const float*)d_in[6];
  const float* b0     = (const float*)d_in[7];
  const float* W1     = (const float*)d_in[8];
  const float* b1     = (const float*)d_in[9];
  const float* W2     = (const float*)d_in[10];
  const float* b2     = (const float*)d_in[11];
  const float* W3     = (const float*)d_in[12];
  const float* b3     = (const float*)d_in[13];
  float* out = (float*)d_out;

  char* ws = (char*)d_ws;
  float* stats = (float*)ws;                 ws += 4096;
  short* XqT   = (short*)ws;                 ws += (long)Bsz * HW * KIN * 2;
  short* XkT   = (short*)ws;                 ws += (long)Bsz * HW * KIN * 2;
  short* Wt0   = (short*)ws;                 ws += (long)KOUT * KIN * 2;
  short* Wt1   = (short*)ws;                 ws += (long)KOUT * KIN * 2;
  short* Wt2   = (short*)ws;                 ws += (long)KOUT * KIN * 2;
  short* Wt3   = (short*)ws;                 ws += (long)Cc * CH3 * 2;
  short* qTb   = (short*)ws;                 ws += (long)Bsz * HW * KOUT * 2;
  short* kTb   = (short*)ws;                 ws += (long)Bsz * HW * KOUT * 2;
  short* vb    = (short*)ws;                 ws += (long)Bsz * KOUT * HW * 2;
  short* hhT   = (short*)ws;                 ws += (long)Bsz * HW * CH3 * 2;

  k_prep_w<<<384, 256, 0, stream>>>(W0, W1, W2, W3, Wt0, Wt1, Wt2, Wt3);
  k_gn_stats<<<512, 256, 0, stream>>>(x, stats);
  k_build_xt<<<dim3(16, 16), 256, 0, stream>>>(x, q_cond, k_a, k_b, gsc, gbi,
                                               stats, XqT, XkT);
  // qT[b][hw][512] = XqT * W0 (+b0)*scale
  k_gemm<<<dim3(4, 8, 16), 256, 0, stream>>>(
      XqT, (long)HW * KIN, Wt0, 0, qTb, (long)HW * KOUT,
      b0, 0, SCALE_Q, HW, KOUT, KIN);
  // kT[b][hw][512]
  k_gemm<<<dim3(4, 8, 16), 256, 0, stream>>>(
      XkT, (long)HW * KIN, Wt1, 0, kTb, (long)HW * KOUT,
      b1, 0, 1.f, HW, KOUT, KIN);
  // v[b][512][1024]
  k_gemm<<<dim3(8, 4, 16), 256, 0, stream>>>(
      Wt2, 0, XkT, (long)HW * KIN, vb, (long)KOUT * HW,
      b2, 1, 1.f, KOUT, HW, KIN);
  k_attn<<<dim3(16, 96), 256, 0, stream>>>(qTb, kTb, vb, hhT);
  k_gemm_final<<<dim3(8, 1, 16), 256, 0, stream>>>(Wt3, hhT, x, b3, out);
}

// Round 3
// 238.734 us; speedup vs baseline: 1.1681x; 1.1681x over previous
//
#include <hip/hip_runtime.h>
#include <hip/hip_bf16.h>

typedef __attribute__((ext_vector_type(8))) short short8;
typedef __attribute__((ext_vector_type(4))) short short4v;
typedef __attribute__((ext_vector_type(4))) float f32x4;

__device__ inline short f2bf(float f) {
  __hip_bfloat16 h = __float2bfloat16(f);
  return __builtin_bit_cast(short, h);
}

__device__ inline f32x4 mfma16(short8 a, short8 b, f32x4 c) {
  return __builtin_amdgcn_mfma_f32_16x16x32_bf16(a, b, c, 0, 0, 0);
}

// ---------------- constants ----------------
#define Bsz 16
#define Cc 128
#define HW 1024
#define NHh 4
#define CONDc 32
#define KIN 160      // C + COND
#define KOUT 512     // C * NH
#define CH3 768      // (NH+2)*C
#define SCALE_Q 0.08838834764831845f   // 1/sqrt(128)

// ---------------- weight prep: transpose + bf16 ----------------
__global__ __launch_bounds__(256) void k_prep_w(
    const float* __restrict__ W0, const float* __restrict__ W1,
    const float* __restrict__ W2, const float* __restrict__ W3,
    short* __restrict__ Wt0, short* __restrict__ Wt1,
    short* __restrict__ Wt2, short* __restrict__ Wt3) {
  int i = blockIdx.x * 256 + threadIdx.x;
  if (i < KOUT * KIN) {           // Wt[ko][c] = W[c][ko]
    int ko = i / KIN, c = i % KIN;
    Wt0[i] = f2bf(W0[c * KOUT + ko]);
    Wt1[i] = f2bf(W1[c * KOUT + ko]);
    Wt2[i] = f2bf(W2[c * KOUT + ko]);
  }
  if (i < Cc * CH3) {             // Wt3[ko][ch] = W3[ch][ko]
    int ko = i / CH3, ch = i % CH3;
    Wt3[i] = f2bf(W3[ch * Cc + ko]);
  }
}

// ---------------- groupnorm stats ----------------
__global__ __launch_bounds__(256) void k_gn_stats(const float* __restrict__ x,
                                                  float* __restrict__ stats) {
  int b = blockIdx.x >> 5, g = blockIdx.x & 31;
  int tid = threadIdx.x, lane = tid & 63, wid = tid >> 6;
  long base = ((long)b * Cc + g * 4) * HW;
  float s = 0.f, sq = 0.f;
#pragma unroll
  for (int i = 0; i < 16; i++) {
    float v = x[base + tid + i * 256];
    s += v; sq += v * v;
  }
#pragma unroll
  for (int d = 1; d < 64; d <<= 1) {
    s += __shfl_xor(s, d);
    sq += __shfl_xor(sq, d);
  }
  __shared__ float ls[8];
  if (lane == 0) { ls[wid] = s; ls[wid + 4] = sq; }
  __syncthreads();
  if (tid == 0) {
    float ts = ls[0] + ls[1] + ls[2] + ls[3];
    float tq = ls[4] + ls[5] + ls[6] + ls[7];
    float mu = ts / 4096.f;
    float var = tq / 4096.f - mu * mu;
    var = var < 0.f ? 0.f : var;
    stats[(b * 32 + g) * 2] = mu;
    stats[(b * 32 + g) * 2 + 1] = rsqrtf(var + 1e-6f);
  }
}

// ---------------- GN apply + concat conds + transpose -> XqT/XkT [b][hw][160] bf16 ----------------
__global__ __launch_bounds__(256) void k_build_xt(
    const float* __restrict__ x, const float* __restrict__ q_cond,
    const float* __restrict__ k_a, const float* __restrict__ k_b,
    const float* __restrict__ gsc, const float* __restrict__ gbi,
    const float* __restrict__ stats,
    short* __restrict__ XqT, short* __restrict__ XkT) {
  int b = blockIdx.y, hw0 = blockIdx.x * 64, tid = threadIdx.x;
  __shared__ short xq[64][KIN];
  __shared__ short xk[64][KIN];
#pragma unroll
  for (int i = 0; i < 8; i++) {
    int ci = tid + i * 256;
    int c = ci >> 4, hwo = (ci & 15) * 4;
    float4 xv = *(const float4*)(x + ((long)b * Cc + c) * HW + hw0 + hwo);
    int g = c >> 2;
    float mu = stats[(b * 32 + g) * 2];
    float rs = stats[(b * 32 + g) * 2 + 1];
    float sc = gsc[c] * rs;
    float bi = gbi[c] - mu * sc;
    short v0 = f2bf(xv.x * sc + bi);
    short v1 = f2bf(xv.y * sc + bi);
    short v2 = f2bf(xv.z * sc + bi);
    short v3 = f2bf(xv.w * sc + bi);
    xq[hwo + 0][c] = v0; xk[hwo + 0][c] = v0;
    xq[hwo + 1][c] = v1; xk[hwo + 1][c] = v1;
    xq[hwo + 2][c] = v2; xk[hwo + 2][c] = v2;
    xq[hwo + 3][c] = v3; xk[hwo + 3][c] = v3;
  }
#pragma unroll
  for (int i = 0; i < 2; i++) {
    int ci = tid + i * 256;
    int cc = ci >> 4, hwo = (ci & 15) * 4;
    long src = ((long)(b >> 1) * CONDc + cc) * HW + hw0 + hwo;
    float4 qv = *(const float4*)(q_cond + src);
    const float* ks = (b & 1) ? k_b : k_a;
    float4 kv = *(const float4*)(ks + src);
    xq[hwo + 0][Cc + cc] = f2bf(qv.x); xk[hwo + 0][Cc + cc] = f2bf(kv.x);
    xq[hwo + 1][Cc + cc] = f2bf(qv.y); xk[hwo + 1][Cc + cc] = f2bf(kv.y);
    xq[hwo + 2][Cc + cc] = f2bf(qv.z); xk[hwo + 2][Cc + cc] = f2bf(kv.z);
    xq[hwo + 3][Cc + cc] = f2bf(qv.w); xk[hwo + 3][Cc + cc] = f2bf(kv.w);
  }
  __syncthreads();
#pragma unroll
  for (int i = 0; i < 5; i++) {
    int ci = tid + i * 256;
    int row = ci / 20, ch = (ci % 20) * 8;
    long dst = ((long)b * HW + hw0 + row) * KIN + ch;
    *(short8*)(XqT + dst) = *(const short8*)(&xq[row][ch]);
    *(short8*)(XkT + dst) = *(const short8*)(&xk[row][ch]);
  }
}

// ---------------- merged QKV GEMM: 3 nin projections in one dispatch ----------------
// z: 0..15 -> q (XqT*W0), 16..31 -> k (XkT*W1), 32..47 -> v (W2*XkT)
// D[m][n] = sum_k A[m][k]*B[n][k]; 128x128 tile, 4 waves (2x2).
__device__ inline int gswz(int row, int kb) {
  return row * 64 + (kb ^ (((row >> 1) & 3) << 4));
}

__global__ __launch_bounds__(256) void k_gemm_qkv(
    const short* __restrict__ XqT, const short* __restrict__ XkT,
    const short* __restrict__ Wt0, const short* __restrict__ Wt1,
    const short* __restrict__ Wt2,
    const float* __restrict__ b0v, const float* __restrict__ b1v,
    const float* __restrict__ b2v,
    short* __restrict__ qTb, short* __restrict__ kTb, short* __restrict__ vb) {
  int z = blockIdx.z, which = z >> 4, b = z & 15;
  const short* A;
  const short* Bm;
  short* D;
  const float* bias;
  float scale = 1.f;
  int m0, n0, ldD, bias_m = 0;
  if (which == 0) {
    A = XqT + (long)b * HW * KIN; Bm = Wt0; D = qTb + (long)b * HW * KOUT;
    bias = b0v; scale = SCALE_Q;
    m0 = blockIdx.y * 128; n0 = blockIdx.x * 128; ldD = KOUT;
  } else if (which == 1) {
    A = XkT + (long)b * HW * KIN; Bm = Wt1; D = kTb + (long)b * HW * KOUT;
    bias = b1v;
    m0 = blockIdx.y * 128; n0 = blockIdx.x * 128; ldD = KOUT;
  } else {
    A = Wt2; Bm = XkT + (long)b * HW * KIN; D = vb + (long)b * KOUT * HW;
    bias = b2v; bias_m = 1;
    m0 = blockIdx.x * 128; n0 = blockIdx.y * 128; ldD = HW;
  }
  int tid = threadIdx.x, lane = tid & 63, wid = tid >> 6;
  int wm = (wid >> 1) * 64, wn = (wid & 1) * 64;
  int lm = lane & 15, kg = lane >> 4;
  __shared__ short lA[128 * 32];
  __shared__ short lB[128 * 32];
  f32x4 acc[4][4] = {};
  for (int k0 = 0; k0 < KIN; k0 += 32) {
    __syncthreads();
#pragma unroll
    for (int i = 0; i < 2; i++) {
      int ci = tid + i * 256;
      int row = ci >> 2, kb = (ci & 3) * 16;
      *(short8*)((char*)lA + gswz(row, kb)) =
          *(const short8*)(A + (long)(m0 + row) * KIN + k0 + (kb >> 1));
      *(short8*)((char*)lB + gswz(row, kb)) =
          *(const short8*)(Bm + (long)(n0 + row) * KIN + k0 + (kb >> 1));
    }
    __syncthreads();
    short8 af[4], bfr[4];
    int kb = kg * 16;
#pragma unroll
    for (int t = 0; t < 4; t++) {
      af[t] = *(const short8*)((char*)lA + gswz(wm + t * 16 + lm, kb));
      bfr[t] = *(const short8*)((char*)lB + gswz(wn + t * 16 + lm, kb));
    }
#pragma unroll
    for (int mt = 0; mt < 4; mt++)
#pragma unroll
      for (int nt = 0; nt < 4; nt++)
        acc[mt][nt] = mfma16(af[mt], bfr[nt], acc[mt][nt]);
  }
#pragma unroll
  for (int mt = 0; mt < 4; mt++)
#pragma unroll
    for (int nt = 0; nt < 4; nt++) {
      f32x4 c = acc[mt][nt];
      int n = n0 + wn + nt * 16 + lm;
#pragma unroll
      for (int r = 0; r < 4; r++) {
        int m = m0 + wm + mt * 16 + kg * 4 + r;
        float val = c[r] + bias[bias_m ? m : n];
        val *= scale;
        D[(long)m * ldD + n] = f2bf(val);
      }
    }
}

// ---------------- final GEMM: out = x + hhT*Wt3 + b3 (f32 out) ----------------
__global__ __launch_bounds__(256) void k_gemm_final(
    const short* __restrict__ A,      // Wt3 [128][768]
    const short* __restrict__ Ball,   // hhT [16][1024][768]
    const float* __restrict__ x, const float* __restrict__ bias,
    float* __restrict__ out) {
  int b = blockIdx.z;
  const short* B = Ball + (long)b * HW * CH3;
  int n0 = blockIdx.x * 128;
  int tid = threadIdx.x, lane = tid & 63, wid = tid >> 6;
  int wm = (wid >> 1) * 64, wn = (wid & 1) * 64;
  int lm = lane & 15, kg = lane >> 4;
  __shared__ short lA[128 * 32];
  __shared__ short lB[128 * 32];
  f32x4 acc[4][4] = {};
  for (int k0 = 0; k0 < CH3; k0 += 32) {
    __syncthreads();
#pragma unroll
    for (int i = 0; i < 2; i++) {
      int ci = tid + i * 256;
      int row = ci >> 2, kb = (ci & 3) * 16;
      *(short8*)((char*)lA + gswz(row, kb)) =
          *(const short8*)(A + (long)row * CH3 + k0 + (kb >> 1));
      *(short8*)((char*)lB + gswz(row, kb)) =
          *(const short8*)(B + (long)(n0 + row) * CH3 + k0 + (kb >> 1));
    }
    __syncthreads();
    short8 af[4], bfr[4];
    int kb = kg * 16;
#pragma unroll
    for (int t = 0; t < 4; t++) {
      af[t] = *(const short8*)((char*)lA + gswz(wm + t * 16 + lm, kb));
      bfr[t] = *(const short8*)((char*)lB + gswz(wn + t * 16 + lm, kb));
    }
#pragma unroll
    for (int mt = 0; mt < 4; mt++)
#pragma unroll
      for (int nt = 0; nt < 4; nt++)
        acc[mt][nt] = mfma16(af[mt], bfr[nt], acc[mt][nt]);
  }
#pragma unroll
  for (int mt = 0; mt < 4; mt++)
#pragma unroll
    for (int nt = 0; nt < 4; nt++) {
      f32x4 c = acc[mt][nt];
      int n = n0 + wn + nt * 16 + lm;
#pragma unroll
      for (int r = 0; r < 4; r++) {
        int m = wm + mt * 16 + kg * 4 + r;   // M=128, m0=0
        float val = c[r] + bias[m];
        long oidx = ((long)b * Cc + m) * HW + n;
        out[oidx] = x[oidx] + val;
      }
    }
}

// ---------------- fused flash attention (swapped QK^T, lane-local softmax) ----------------
// grid: (16 q-tiles, 96 problems). block 256 = 4 waves x 16 q rows.
// S^T = mfma(K, Q): lane (lm, kg) holds S[q = q0+wid*16+lm][kv = nt*16+kg*4+r]
// -> full row owned per lane-column; softmax reduce = 15 local + 2 shfl.
__global__ __launch_bounds__(256) void k_attn(
    const short* __restrict__ qT, const short* __restrict__ kT,
    const short* __restrict__ v, short* __restrict__ hhT) {
  int p = blockIdx.y;
  int b4 = p / 24, rem = p % 24, j = rem >> 2, e = rem & 3;
  static const int qsl[6] = {0, 1, 2, 3, 0, 2};
  static const int kvl[6] = {1, 0, 3, 2, 2, 0};
  int bq = b4 * 4 + qsl[j];
  int bkv = b4 * 4 + kvl[j];
  int midx = 4 * j + e;
  int bo = b4 * 4 + midx / 6;
  int chb = (midx % 6) * Cc;
  int q0 = blockIdx.x * 64;
  int tid = threadIdx.x, lane = tid & 63, wid = tid >> 6;
  int lm = lane & 15, kg = lane >> 4;

  __shared__ char lK[64 * 256];     // K^T tile [kv][c] bf16, swizzled
  __shared__ char lV[128 * 128];    // V tile [c][kv] bf16, swizzled
  __shared__ char lP[4][2048];      // per-wave P [q][kv] bf16, swizzled

  // Q fragments (B-operand): B[n=q][k=c], 4 k-windows of 32
  short8 qf[4];
  const short* qbase =
      qT + ((long)bq * HW + q0 + wid * 16 + lm) * KOUT + e * Cc + kg * 8;
#pragma unroll
  for (int ks = 0; ks < 4; ks++) qf[ks] = *(const short8*)(qbase + ks * 32);

  float mrow = -3e38f, lsum = 0.f;
  f32x4 oacc[8] = {};

  for (int kvt = 0; kvt < 16; kvt++) {
    int kv0 = kvt * 64;
    __syncthreads();
    // stage K^T tile: 64 rows x 256B
#pragma unroll
    for (int i = 0; i < 4; i++) {
      int ci = tid + i * 256;
      int row = ci >> 4, cb = (ci & 15) * 16;
      *(short8*)(lK + row * 256 + (cb ^ ((row & 7) << 4))) =
          *(const short8*)(kT + ((long)bkv * HW + kv0 + row) * KOUT + e * Cc + (cb >> 1));
    }
    // stage V tile: 128 rows x 128B
#pragma unroll
    for (int i = 0; i < 4; i++) {
      int ci = tid + i * 256;
      int row = ci >> 3, kvb = (ci & 7) * 16;
      *(short8*)(lV + row * 128 + (kvb ^ ((row & 7) << 4))) =
          *(const short8*)(v + ((long)bkv * KOUT + e * Cc + row) * HW + kv0 + (kvb >> 1));
    }
    __syncthreads();
    // S^T = K Q : D[kv 64][q 16] -> lane holds 16 kv-values of ONE q row
    f32x4 s[4] = {};
#pragma unroll
    for (int ks = 0; ks < 4; ks++) {
      int cbyte = ks * 64 + kg * 16;
#pragma unroll
      for (int nt = 0; nt < 4; nt++) {
        int row = nt * 16 + lm;
        short8 kf = *(const short8*)(lK + row * 256 + (cbyte ^ ((row & 7) << 4)));
        s[nt] = mfma16(kf, qf[ks], s[nt]);   // swapped: A=K, B=Q
      }
    }
    // lane-local online softmax for q = lm row
    float mx = -3e38f;
#pragma unroll
    for (int nt = 0; nt < 4; nt++)
#pragma unroll
      for (int r = 0; r < 4; r++) mx = fmaxf(mx, s[nt][r]);
    mx = fmaxf(mx, __shfl_xor(mx, 16));
    mx = fmaxf(mx, __shfl_xor(mx, 32));
    if (mx > mrow + 8.f) {                   // defer-max (T13, THR=8)
      float corr = __expf(mrow - mx);
      mrow = mx;
      lsum *= corr;
#pragma unroll
      for (int ct = 0; ct < 8; ct++) oacc[ct] *= corr;
    }
    float ps = 0.f;
#pragma unroll
    for (int nt = 0; nt < 4; nt++)
#pragma unroll
      for (int r = 0; r < 4; r++) {
        float pv = __expf(s[nt][r] - mrow);
        s[nt][r] = pv;
        ps += pv;
      }
    ps += __shfl_xor(ps, 16);
    ps += __shfl_xor(ps, 32);
    lsum += ps;
    // P -> per-wave LDS [q][kv] bf16 swizzled, vectorized 8B writes
#pragma unroll
    for (int nt = 0; nt < 4; nt++) {
      short4v pk;
#pragma unroll
      for (int r = 0; r < 4; r++) pk[r] = f2bf(s[nt][r]);
      int kvb = (nt * 16 + kg * 4) * 2;
      *(short4v*)(lP[wid] + lm * 128 + (kvb ^ ((lm & 7) << 4))) = pk;
    }
    // O^T += V P : D[c 128][q 16] -> oacc[ct][r] = O[q=lm][c=ct*16+kg*4+r]
#pragma unroll
    for (int ks2 = 0; ks2 < 2; ks2++) {
      int kvbyte = ks2 * 64 + kg * 16;
      short8 pf = *(const short8*)(lP[wid] + lm * 128 + (kvbyte ^ ((lm & 7) << 4)));
#pragma unroll
      for (int ct = 0; ct < 8; ct++) {
        int row = ct * 16 + lm;
        short8 vf = *(const short8*)(lV + row * 128 + (kvbyte ^ ((row & 7) << 4)));
        oacc[ct] = mfma16(vf, pf, oacc[ct]);  // swapped: A=V, B=P
      }
    }
  }
  // epilogue: lane owns q = q0+wid*16+lm; c = ct*16 + kg*4 + r -> 8B stores
  float inv = 1.f / lsum;
  long obase = ((long)bo * HW + q0 + wid * 16 + lm) * CH3 + chb + kg * 4;
#pragma unroll
  for (int ct = 0; ct < 8; ct++) {
    short4v pk;
#pragma unroll
    for (int r = 0; r < 4; r++) pk[r] = f2bf(oacc[ct][r] * inv);
    *(short4v*)(hhT + obase + ct * 16) = pk;
  }
}

// ---------------- launcher ----------------
extern "C" void kernel_launch(void* const* d_in, const int* in_sizes, int n_in,
                              void* d_out, int out_size, void* d_ws, size_t ws_size,
                              hipStream_t stream) {
  const float* x      = (const float*)d_in[0];
  const float* q_cond = (const float*)d_in[1];
  const float* k_a    = (const float*)d_in[2];
  const float* k_b    = (const float*)d_in[3];
  const float* gsc    = (const float*)d_in[4];
  const float* gbi    = (const float*)d_in[5];
  const float* W0     = (const float*)d_in[6];
  const float* b0     = (const float*)d_in[7];
  const float* W1     = (const float*)d_in[8];
  const float* b1     = (const float*)d_in[9];
  const float* W2     = (const float*)d_in[10];
  const float* b2     = (const float*)d_in[11];
  const float* W3     = (const float*)d_in[12];
  const float* b3     = (const float*)d_in[13];
  float* out = (float*)d_out;

  char* ws = (char*)d_ws;
  float* stats = (float*)ws;                 ws += 4096;
  short* XqT   = (short*)ws;                 ws += (long)Bsz * HW * KIN * 2;
  short* XkT   = (short*)ws;                 ws += (long)Bsz * HW * KIN * 2;
  short* Wt0   = (short*)ws;                 ws += (long)KOUT * KIN * 2;
  short* Wt1   = (short*)ws;                 ws += (long)KOUT * KIN * 2;
  short* Wt2   = (short*)ws;                 ws += (long)KOUT * KIN * 2;
  short* Wt3   = (short*)ws;                 ws += (long)Cc * CH3 * 2;
  short* qTb   = (short*)ws;                 ws += (long)Bsz * HW * KOUT * 2;
  short* kTb   = (short*)ws;                 ws += (long)Bsz * HW * KOUT * 2;
  short* vb    = (short*)ws;                 ws += (long)Bsz * KOUT * HW * 2;
  short* hhT   = (short*)ws;                 ws += (long)Bsz * HW * CH3 * 2;

  k_prep_w<<<384, 256, 0, stream>>>(W0, W1, W2, W3, Wt0, Wt1, Wt2, Wt3);
  k_gn_stats<<<512, 256, 0, stream>>>(x, stats);
  k_build_xt<<<dim3(16, 16), 256, 0, stream>>>(x, q_cond, k_a, k_b, gsc, gbi,
                                               stats, XqT, XkT);
  k_gemm_qkv<<<dim3(4, 8, 48), 256, 0, stream>>>(
      XqT, XkT, Wt0, Wt1, Wt2, b0, b1, b2, qTb, kTb, vb);
  k_attn<<<dim3(16, 96), 256, 0, stream>>>(qTb, kTb, vb, hhT);
  k_gemm_final<<<dim3(8, 1, 16), 256, 0, stream>>>(Wt3, hhT, x, b3, out);
}